// Round 9
// baseline (773.181 us; speedup 1.0000x reference)
//
#include <hip/hip_runtime.h>
#include <hip/hip_bf16.h>

// FSAS_26766236188756 — round 14: r13 + spill-kill. Two deltas vs r13 (passing,
// 270us k3): (1) aA/aB get FRESH definitions at phase-C start (load chunk 4/5
// from L2-hot WS) so they are dead across phase B -> ~32 fewer live VGPRs in the
// hottest region (r13 still spilled ~40 regs = ~92MB hidden WRITE traffic).
// The q/k loop's prefetch-copy becomes dead code (DCE) — no UB, values identical.
// (2) __launch_bounds__(256,3): VGPR cap 170 fits the ~140-reg live set without
// forced spill, LDS 3x51,200 fits -> 3 blocks/CU.
// kx: x [b][c][hw] fp32 -> XT [b][hw][c] bf16
// k0: WPS hi/lo mfma-swizzled w_proj; WS mfma-swizzled w_hidden; wdwT [9][384]
// k3: per-patch 1x1-conv(MFMA) + dw 3x3 + circ conv + LN + *v + proj(MFMA) -> outT
// k4: outT [b][p][px][o] -> out [b][o][row][col]

typedef unsigned short ushort;
typedef __attribute__((ext_vector_type(8))) short short8;
typedef __attribute__((ext_vector_type(4))) float floatx4;
typedef __attribute__((ext_vector_type(2))) unsigned int uint2v;
typedef __attribute__((ext_vector_type(4))) unsigned int uint4v;

#define CC 64
#define HW 65536
#define QSU 68     // qb/kb row stride (ushorts, bf16)
#define TS 68      // t row stride (floats)
#define HS 68      // halo row stride (ushorts)
#define TBS 136    // tB row stride (ushorts): 272B, 16B-aligned
#define OSS 68     // outS row stride (floats)

#define WPSH_OFF 0
#define WPSL_OFF 16384
#define WS_OFF 32768
#define WDWT_OFF 81920
#define XT_OFF  131072
#define XT_BYTES (4ull * HW * 64 * 2)
#define OUTT_OFF (XT_OFF + XT_BYTES)

__device__ __forceinline__ float bu2f(ushort u) {
    union { float f; unsigned i; } v; v.i = ((unsigned)u) << 16; return v.f;
}
__device__ __forceinline__ ushort f2bu(float f) {
    __hip_bfloat16 h = __float2bfloat16(f);
    return *(ushort*)&h;
}
__device__ __forceinline__ float ubits(unsigned u) {
    union { unsigned i; float f; } v; v.i = u; return v.f;
}
__device__ __forceinline__ void unpk(unsigned d, float& lo, float& hi) {
    lo = ubits(d << 16); hi = ubits(d & 0xffff0000u);
}

__global__ __launch_bounds__(256) void kx_tr(
    const float* __restrict__ x, ushort* __restrict__ XT) {
    int b = blockIdx.y;
    int hw = blockIdx.x * 256 + threadIdx.x;
    const float* xb = x + ((size_t)b * CC) * HW;
    ushort* XTb = XT + ((size_t)b * HW + hw) * 64;
#pragma unroll 2
    for (int c0 = 0; c0 < 64; c0 += 8) {
        ushort v[8];
#pragma unroll
        for (int j = 0; j < 8; j++)
            v[j] = f2bu(xb[(size_t)(c0 + j) * HW + hw]);
        *(short8*)(XTb + c0) = *(short8*)v;
    }
}

// k0 (grid 16): WPS hi/lo swizzled w_proj bf16; WS swizzled w_hidden; wdwT [9][384]
__global__ __launch_bounds__(256) void k0_prep(
    const float* __restrict__ wp, const float* __restrict__ wh,
    const float* __restrict__ wdw,
    ushort* __restrict__ WPSH, ushort* __restrict__ WPSL,
    ushort* __restrict__ WS, float* __restrict__ wdwT) {
    int t0 = blockIdx.x * 256 + threadIdx.x;
    for (int i = t0; i < 8192; i += 4096) {
        int j = i & 7;
        int lane = (i >> 3) & 63;
        int ks = (i >> 9) & 3;
        int mt = i >> 11;
        int o = mt * 16 + (lane & 15);
        int cc = ks * 32 + ((lane >> 4) << 3) + j;
        float w = wp[o * 128 + cc];
        ushort hi = f2bu(w);
        WPSH[i] = hi;
        WPSL[i] = f2bu(w - bu2f(hi));
    }
    for (int i = t0; i < 24576; i += 4096) {
        int j = i & 7;
        int lane = (i >> 3) & 63;
        int ks = (i >> 9) & 1;
        int mt = i >> 10;
        int o = mt * 16 + (lane & 15);
        int k = ks * 32 + ((lane >> 4) << 3) + j;
        WS[i] = f2bu(wh[o * 64 + k]);
    }
    for (int i = t0; i < 3456; i += 4096) {
        int k = i / 384, ch = i - k * 384;
        wdwT[i] = wdw[ch * 9 + k];
    }
}

// ---------- fused k3 helpers ----------

__device__ __forceinline__ void load_afrags(short8 (&a)[4][2],
        const ushort* __restrict__ WSg, int ci, int lane) {
#pragma unroll
    for (int mt = 0; mt < 4; mt++) {
        int mtg = ci * 4 + mt;
#pragma unroll
        for (int ks = 0; ks < 2; ks++)
            a[mt][ks] = *(const short8*)(WSg + ((((mtg << 1) + ks) << 6) + lane) * 8);
    }
}

// 1x1 conv for one 64-ch chunk via MFMA; B-operand from registers.
__device__ __forceinline__ void hid_mfma_store(
    ushort* halo_u, const short8 (&a)[4][2], const short8 (&bfr)[2][2],
    const bool (&img)[2], const bool (&live)[2], const int (&pxv)[2],
    const float* __restrict__ bh, int ci, int wave, int quad) {
#pragma unroll
    for (int s = 0; s < 2; s++) {
        if (wave + s * 4 > 6) continue;          // 7 active n-tiles (112 px >= 100)
        floatx4 acc[4];
#pragma unroll
        for (int mt = 0; mt < 4; mt++) {
            acc[mt] = (floatx4){0.f, 0.f, 0.f, 0.f};
            acc[mt] = __builtin_amdgcn_mfma_f32_16x16x32_bf16(a[mt][0], bfr[s][0], acc[mt], 0, 0, 0);
            acc[mt] = __builtin_amdgcn_mfma_f32_16x16x32_bf16(a[mt][1], bfr[s][1], acc[mt], 0, 0, 0);
        }
        int px = pxv[s];
#pragma unroll
        for (int mt = 0; mt < 4; mt++) {
            int chl = mt * 16 + quad * 4;
            float4 bv = *(const float4*)(bh + ci * 64 + chl);
            unsigned d0 = 0u, d1 = 0u;
            if (img[s]) {
                d0 = (unsigned)f2bu(acc[mt][0] + bv.x) | ((unsigned)f2bu(acc[mt][1] + bv.y) << 16);
                d1 = (unsigned)f2bu(acc[mt][2] + bv.z) | ((unsigned)f2bu(acc[mt][3] + bv.w) << 16);
            }
            if (live[s])
                *(uint2v*)(halo_u + px * HS + chl) = (uint2v){d0, d1};
        }
    }
}

// dw 3x3 for 64 q-or-k channels. FMA order identical to old k2.
__device__ __forceinline__ void dw_qk(const ushort* halo_u, ushort* dst,
        const float* __restrict__ wdwT, const float* __restrict__ bdw,
        int gcb, int rowbase, int tid) {
    int c2 = tid & 31, po = tid >> 5;
    int gch = gcb + c2 * 2;
    float w0[9], w1[9];
#pragma unroll
    for (int k = 0; k < 9; k++) {
        w0[k] = wdwT[k * 384 + gch];
        w1[k] = wdwT[k * 384 + gch + 1];
    }
    float b0 = bdw[gch], b1 = bdw[gch + 1];
    float a0[8], a1[8];
#pragma unroll
    for (int c = 0; c < 8; c++) { a0[c] = b0; a1[c] = b1; }
#pragma unroll
    for (int dr = 0; dr < 3; dr++) {
        int hb = (po + dr) * 10;
        float hx[10], hy[10];
#pragma unroll
        for (int i = 0; i < 10; i++) {
            unsigned d = *(const unsigned*)(halo_u + (hb + i) * HS + c2 * 2);
            unpk(d, hx[i], hy[i]);
        }
#pragma unroll
        for (int c = 0; c < 8; c++)
#pragma unroll
            for (int dc = 0; dc < 3; dc++) {
                a0[c] += w0[dr * 3 + dc] * hx[c + dc];
                a1[c] += w1[dr * 3 + dc] * hy[c + dc];
            }
    }
    ushort* r0p = dst + (rowbase + c2 * 2) * QSU + po * 8;
    ushort* r1p = r0p + QSU;
    unsigned p0 = (unsigned)f2bu(a0[0]) | ((unsigned)f2bu(a0[1]) << 16);
    unsigned p1 = (unsigned)f2bu(a0[2]) | ((unsigned)f2bu(a0[3]) << 16);
    unsigned p2 = (unsigned)f2bu(a0[4]) | ((unsigned)f2bu(a0[5]) << 16);
    unsigned p3 = (unsigned)f2bu(a0[6]) | ((unsigned)f2bu(a0[7]) << 16);
    *(uint2v*)(r0p) = (uint2v){p0, p1};
    *(uint2v*)(r0p + 4) = (uint2v){p2, p3};
    p0 = (unsigned)f2bu(a1[0]) | ((unsigned)f2bu(a1[1]) << 16);
    p1 = (unsigned)f2bu(a1[2]) | ((unsigned)f2bu(a1[3]) << 16);
    p2 = (unsigned)f2bu(a1[4]) | ((unsigned)f2bu(a1[5]) << 16);
    p3 = (unsigned)f2bu(a1[6]) | ((unsigned)f2bu(a1[7]) << 16);
    *(uint2v*)(r1p) = (uint2v){p0, p1};
    *(uint2v*)(r1p + 4) = (uint2v){p2, p3};
}

// dw 3x3 for 64 v channels + LN-apply, results kept in registers (tp[16]).
__device__ __forceinline__ void dw_v_collect(const ushort* halo_u, const float* tb,
        const float* __restrict__ wdwT, const float* __restrict__ bdw,
        const float* __restrict__ lnw, const float* __restrict__ lnb,
        int gcb, int pix, int cj, float mu, float rsig, float (&tp)[16]) {
    int r = pix >> 3, cs = pix & 7;
    int ch0 = __builtin_amdgcn_readfirstlane(gcb + cj * 16);
    int ccs = ch0 - 256;
    float acc[16];
#pragma unroll
    for (int jj = 0; jj < 16; jj++) acc[jj] = bdw[ch0 + jj];
#pragma unroll
    for (int dr = 0; dr < 3; dr++) {
#pragma unroll
        for (int dc = 0; dc < 3; dc++) {
            int npx = (r + dr) * 10 + cs + dc;
            const ushort* hp = halo_u + npx * HS + cj * 16;
            uint2v d0 = *(const uint2v*)(hp);
            uint2v d1 = *(const uint2v*)(hp + 4);
            uint2v d2 = *(const uint2v*)(hp + 8);
            uint2v d3 = *(const uint2v*)(hp + 12);
            unsigned dd[8] = {d0.x, d0.y, d1.x, d1.y, d2.x, d2.y, d3.x, d3.y};
#pragma unroll
            for (int jj = 0; jj < 16; jj++) {
                unsigned u = dd[jj >> 1];
                float hv = (jj & 1) ? ubits(u & 0xffff0000u) : ubits(u << 16);
                acc[jj] += wdwT[(dr * 3 + dc) * 384 + ch0 + jj] * hv;
            }
        }
    }
#pragma unroll
    for (int jj = 0; jj < 16; jj++) {
        int cc = ccs + jj;
        float vv = bu2f(f2bu(acc[jj]));   // v passes through bf16 (matches old pipeline)
        float tv = tb[cc * TS + pix];
        tp[jj] = ((tv - mu) * rsig * lnw[cc] + lnb[cc]) * vv;
    }
}

__device__ __forceinline__ void split_store(ushort* tBh, ushort* tBl,
        const float (&tp)[16], int pix, int colbase) {
    ushort hi[16], lo[16];
#pragma unroll
    for (int jj = 0; jj < 16; jj++) {
        ushort h = f2bu(tp[jj]);
        hi[jj] = h;
        lo[jj] = f2bu(tp[jj] - bu2f(h));
    }
    *(short8*)(tBh + pix * TBS + colbase) = *(short8*)hi;
    *(short8*)(tBh + pix * TBS + colbase + 8) = *(short8*)(hi + 8);
    *(short8*)(tBl + pix * TBS + colbase) = *(short8*)lo;
    *(short8*)(tBl + pix * TBS + colbase + 8) = *(short8*)(lo + 8);
}

// k3: fully fused. grid (1024, 4) = (patch, batch). LDS 51,200B -> 3 blk/CU.
// launch_bounds (256,3): VGPR cap 170 fits phase-B live set (~140) w/o spill.
__global__ __launch_bounds__(256, 3) void k3_mega(
    const ushort* __restrict__ XT0, const ushort* __restrict__ WSg,
    const float* __restrict__ bh,
    const ushort* __restrict__ WPSH, const ushort* __restrict__ WPSL,
    const float* __restrict__ bp, const float* __restrict__ lnw,
    const float* __restrict__ lnb, const float* __restrict__ wdwT,
    const float* __restrict__ bdw, float* __restrict__ outT) {
    __shared__ float SH[12800];            // 51,200 B
    ushort* qb_u = (ushort*)SH;            // bf16 [128][68]   bytes 0..17407
    ushort* kb_u = (ushort*)SH + 8704;     // bf16 [128][68]   bytes 17408..34815
    float* tb = SH;                        // f32 [128][68] overlay (after B)
    float* red = SH + 8704;                // 512 f            bytes 34816..36863
    ushort* halo_u = (ushort*)SH + 18432;  // [100][68]u       bytes 36864..50463
    ushort* tBh = (ushort*)SH;             // [64][136]u overlay of tb (after D)
    ushort* tBl = (ushort*)SH + 8704;      // [64][136]u
    float* outS = SH;                      // [64][68] f32 overlay (after E MFMA)

    int tid = threadIdx.x;
    int lane = tid & 63, wave = tid >> 6;
    int lane15 = lane & 15, quad = lane >> 4;
    int b = blockIdx.y;
    const ushort* XT = XT0 + (size_t)b * HW * 64;
    int bid = blockIdx.x;
    int p = ((bid & 7) << 7) | (bid >> 3);   // XCD swizzle
    int prow = p >> 5, pcol = p & 31;
    int r0 = prow * 8, c0 = pcol * 8;

    // ---- B-fragments (x-patch) -> registers, once for all 6 chunks ----
    short8 bfr[2][2];
    bool img[2], live[2];
    int pxv[2];
#pragma unroll
    for (int s = 0; s < 2; s++) {
        int nt = wave + s * 4;
        int px = nt * 16 + lane15;
        pxv[s] = px;
        live[s] = (nt <= 6) && (px < 100);
        int hr = px / 10, hc = px - hr * 10;
        int gr = r0 - 1 + hr, gc = c0 - 1 + hc;
        img[s] = live[s] && ((unsigned)gr < 256u) && ((unsigned)gc < 256u);
        size_t gidx = img[s] ? (size_t)(gr * 256 + gc) * 64 : 0;
        short8 z = (short8){0, 0, 0, 0, 0, 0, 0, 0};
        short8 t0 = *(const short8*)(XT + gidx + quad * 8);
        short8 t1 = *(const short8*)(XT + gidx + 32 + quad * 8);
        bfr[s][0] = img[s] ? t0 : z;
        bfr[s][1] = img[s] ? t1 : z;
    }

    // ---- q/k: 4 chunks of {1x1 MFMA -> halo, dw 3x3 -> qb/kb}; a-frags dbuf ----
    short8 aA[4][2], aB[4][2];
    load_afrags(aA, WSg, 0, lane);
#pragma unroll
    for (int ci = 0; ci < 4; ci++) {
        if (ci) __syncthreads();
        hid_mfma_store(halo_u, aA, bfr, img, live, pxv, bh, ci, wave, quad);
        load_afrags(aB, WSg, ci + 1, lane);
        __syncthreads();
        dw_qk(halo_u, (ci < 2 ? qb_u : kb_u), wdwT, bdw, ci * 64, (ci & 1) * 64, tid);
#pragma unroll
        for (int mt = 0; mt < 4; mt++)
#pragma unroll
            for (int ks = 0; ks < 2; ks++) aA[mt][ks] = aB[mt][ks];
    }
    __syncthreads();

    // ---- Phase B: 2D circular conv (fully unrolled, qr statically indexed) ----
    int c = tid >> 1, h = tid & 1;
    float qr[64];
    {
        const ushort* qrow = qb_u + c * QSU;
#pragma unroll
        for (int j = 0; j < 16; j++) {
            uint2v d = *(const uint2v*)(qrow + 4 * j);
            unpk(d.x, qr[4 * j], qr[4 * j + 1]);
            unpk(d.y, qr[4 * j + 2], qr[4 * j + 3]);
        }
    }
    float acc[8][4];
#pragma unroll
    for (int r = 0; r < 8; r++)
#pragma unroll
        for (int sc = 0; sc < 4; sc++) acc[r][sc] = 0.f;
    {
        const ushort* krow = kb_u + c * QSU;
#pragma unroll
        for (int m = 0; m < 8; m++) {
            float kr[8];
#pragma unroll
            for (int u2 = 0; u2 < 4; u2++) {
                int colo = (u2 * 2 + 4 * h) & 7;
                unsigned d = *(const unsigned*)(krow + m * 8 + colo);
                unpk(d, kr[u2 * 2], kr[u2 * 2 + 1]);
            }
#pragma unroll
            for (int r = 0; r < 8; r++) {
                int i = (r - m) & 7;
#pragma unroll
                for (int sc = 0; sc < 4; sc++)
#pragma unroll
                    for (int j = 0; j < 8; j++)
                        acc[r][sc] += qr[i * 8 + j] * kr[(sc - j) & 7];
            }
        }
    }
    __syncthreads();                          // B reads done -> tb overlay safe

    // ---- Phase C: FRESH a-frag defs (kills aA/aB liveness across B);
    //      t -> tb; chunk-4 MFMA into halo; chunk-5 frags ----
    load_afrags(aA, WSg, 4, lane);            // redefinition: chunk 4 (same values
                                              // the loop prefetched; loop copy DCEs)
#pragma unroll
    for (int r = 0; r < 8; r++) {
        float4 v = {acc[r][0], acc[r][1], acc[r][2], acc[r][3]};
        *(float4*)(tb + c * TS + r * 8 + h * 4) = v;
    }
    hid_mfma_store(halo_u, aA, bfr, img, live, pxv, bh, 4, wave, quad);
    load_afrags(aB, WSg, 5, lane);            // redefinition: chunk 5
    __syncthreads();                          // tb ready AND halo4 ready

    // ---- LN stats ----
    int pix = tid & 63, cg = tid >> 6;
    float sum = 0.f, sq = 0.f;
#pragma unroll
    for (int j = 0; j < 32; j++) {
        int cc = cg * 32 + j;
        float v = tb[cc * TS + pix];
        sum += v; sq += v * v;
    }
    red[cg * 64 + pix] = sum;
    red[256 + cg * 64 + pix] = sq;
    __syncthreads();
    float ts = red[pix] + red[64 + pix] + red[128 + pix] + red[192 + pix];
    float tq = red[256 + pix] + red[320 + pix] + red[384 + pix] + red[448 + pix];
    float mu = ts * (1.f / 128.f);
    float var = tq * (1.f / 128.f) - mu * mu;
    float rsig = rsqrtf(var + 1e-5f);

    // ---- v chunks 4,5: dw + LN-apply -> registers ----
    float tpA[16], tpB[16];
    dw_v_collect(halo_u, tb, wdwT, bdw, lnw, lnb, 256, pix, cg, mu, rsig, tpA);
    __syncthreads();                          // halo4 reads done
    hid_mfma_store(halo_u, aB, bfr, img, live, pxv, bh, 5, wave, quad);
    __syncthreads();                          // halo5 ready
    dw_v_collect(halo_u, tb, wdwT, bdw, lnw, lnb, 320, pix, cg, mu, rsig, tpB);
    __syncthreads();                          // ALL tb reads + halo reads done

    // ---- D3: bf16 hi/lo split of t, px-major into tB (overlay of tb) ----
    split_store(tBh, tBl, tpA, pix, cg * 16);
    split_store(tBh, tBl, tpB, pix, 64 + cg * 16);
    __syncthreads();                          // tB ready

    // ---- Phase E: proj 64x64x128 via MFMA (hi/lo 3-term) ----
    short8 bhf[4], blf[4];
#pragma unroll
    for (int ks = 0; ks < 4; ks++) {
        const int rb = (wave * 16 + lane15) * TBS + ks * 32 + quad * 8;
        bhf[ks] = *(const short8*)(tBh + rb);
        blf[ks] = *(const short8*)(tBl + rb);
    }
    floatx4 pacc[4];
#pragma unroll
    for (int mt = 0; mt < 4; mt++) {
        float4 bv = *(const float4*)(bp + mt * 16 + quad * 4);
        pacc[mt] = (floatx4){bv.x, bv.y, bv.z, bv.w};
    }
#pragma unroll
    for (int mt = 0; mt < 4; mt++) {
#pragma unroll
        for (int ks = 0; ks < 4; ks++) {
            short8 ah = *(const short8*)(WPSH + (((mt * 4 + ks) << 6) + lane) * 8);
            short8 al = *(const short8*)(WPSL + (((mt * 4 + ks) << 6) + lane) * 8);
            pacc[mt] = __builtin_amdgcn_mfma_f32_16x16x32_bf16(ah, bhf[ks], pacc[mt], 0, 0, 0);
            pacc[mt] = __builtin_amdgcn_mfma_f32_16x16x32_bf16(ah, blf[ks], pacc[mt], 0, 0, 0);
            pacc[mt] = __builtin_amdgcn_mfma_f32_16x16x32_bf16(al, bhf[ks], pacc[mt], 0, 0, 0);
        }
    }
    __syncthreads();                          // all tB reads done -> outS overlay safe

    // ---- stage to outS [px][o] and write outT contiguously ----
#pragma unroll
    for (int mt = 0; mt < 4; mt++) {
        float4 v = {pacc[mt][0], pacc[mt][1], pacc[mt][2], pacc[mt][3]};
        *(float4*)(outS + (wave * 16 + lane15) * OSS + mt * 16 + quad * 4) = v;
    }
    __syncthreads();
    {
        int px = tid >> 2, oq = (tid & 3) * 16;
        float* g = outT + ((size_t)(b * 1024 + p) * 64 + px) * 64 + oq;
        const float* srow = outS + px * OSS + oq;
#pragma unroll
        for (int k = 0; k < 4; k++)
            *(float4*)(g + k * 4) = *(const float4*)(srow + k * 4);
    }
}

// k4: outT [b][p][px][o] -> out [b][o][row][col]. grid (64, 4), 256 thr.
__global__ __launch_bounds__(256) void k4_tr(
    const float* __restrict__ outT, float* __restrict__ out) {
    int b = blockIdx.y;
    int xb = blockIdx.x;
    int pr = xb >> 1, half = xb & 1;
    int tid = threadIdx.x;
    int c128 = tid & 127, rr = tid >> 7;
    int col = half * 128 + c128;
    int p = pr * 32 + (col >> 3);
    int cs = col & 7;
    const float* tbase = outT + (size_t)(b * 1024 + p) * 4096;
    float* obase = out + ((size_t)b * 64) * 65536 + col;
#pragma unroll
    for (int r4 = 0; r4 < 4; r4++) {
        int r = rr * 4 + r4;
        int px = r * 8 + cs;
        const float* src = tbase + (size_t)px * 64;
        float v[64];
#pragma unroll
        for (int k = 0; k < 16; k++)
            *(float4*)(v + k * 4) = *(const float4*)(src + k * 4);
        float* dst = obase + (size_t)(pr * 8 + r) * 256;
#pragma unroll
        for (int o = 0; o < 64; o++)
            dst[(size_t)o * 65536] = v[o];
    }
}

extern "C" void kernel_launch(void* const* d_in, const int* in_sizes, int n_in,
                              void* d_out, int out_size, void* d_ws, size_t ws_size,
                              hipStream_t stream) {
    (void)in_sizes; (void)n_in; (void)out_size; (void)ws_size;
    const float* x   = (const float*)d_in[0];
    const float* wh  = (const float*)d_in[1];
    const float* bh  = (const float*)d_in[2];
    const float* wdw = (const float*)d_in[3];
    const float* bdw = (const float*)d_in[4];
    const float* wp  = (const float*)d_in[5];
    const float* bp  = (const float*)d_in[6];
    const float* lnw = (const float*)d_in[7];
    const float* lnb = (const float*)d_in[8];
    float* out = (float*)d_out;

    char* ws = (char*)d_ws;
    ushort* WPSH = (ushort*)(ws + WPSH_OFF);
    ushort* WPSL = (ushort*)(ws + WPSL_OFF);
    ushort* WS = (ushort*)(ws + WS_OFF);
    float* wdwT = (float*)(ws + WDWT_OFF);
    ushort* XT = (ushort*)(ws + XT_OFF);
    float* outT = (float*)(ws + OUTT_OFF);

    kx_tr<<<dim3(256, 4), dim3(256), 0, stream>>>(x, XT);
    k0_prep<<<dim3(16), dim3(256), 0, stream>>>(wp, wh, wdw, WPSH, WPSL, WS, wdwT);
    k3_mega<<<dim3(1024, 4), dim3(256), 0, stream>>>(
        XT, WS, bh, WPSH, WPSL, bp, lnw, lnb, wdwT, bdw, outT);
    k4_tr<<<dim3(64, 4), dim3(256), 0, stream>>>(outT, out);
}

// Round 10
// 407.177 us; speedup vs baseline: 1.8989x; 1.8989x over previous
//
#include <hip/hip_runtime.h>
#include <hip/hip_bf16.h>

// FSAS_26766236188756 — round 15: r13 config + r14's (correctness-verified)
// fresh a-frag defs ONLY. r14's launch_bounds(256,3) capped VGPR below the real
// live set -> allocator gave up on qr (VGPR 84, 2.2GB scratch traffic, 613us).
// Here: __launch_bounds__(256,2) (the 270us config) + aA/aB redefined at phase C
// so they are dead across phase B (~32 fewer live regs -> less residual spill).
// kx: x [b][c][hw] fp32 -> XT [b][hw][c] bf16
// k0: WPS hi/lo mfma-swizzled w_proj; WS mfma-swizzled w_hidden; wdwT [9][384]
// k3: per-patch 1x1-conv(MFMA) + dw 3x3 + circ conv + LN + *v + proj(MFMA) -> outT
// k4: outT [b][p][px][o] -> out [b][o][row][col]

typedef unsigned short ushort;
typedef __attribute__((ext_vector_type(8))) short short8;
typedef __attribute__((ext_vector_type(4))) float floatx4;
typedef __attribute__((ext_vector_type(2))) unsigned int uint2v;
typedef __attribute__((ext_vector_type(4))) unsigned int uint4v;

#define CC 64
#define HW 65536
#define QSU 68     // qb/kb row stride (ushorts, bf16)
#define TS 68      // t row stride (floats)
#define HS 68      // halo row stride (ushorts)
#define TBS 136    // tB row stride (ushorts): 272B, 16B-aligned
#define OSS 68     // outS row stride (floats)

#define WPSH_OFF 0
#define WPSL_OFF 16384
#define WS_OFF 32768
#define WDWT_OFF 81920
#define XT_OFF  131072
#define XT_BYTES (4ull * HW * 64 * 2)
#define OUTT_OFF (XT_OFF + XT_BYTES)

__device__ __forceinline__ float bu2f(ushort u) {
    union { float f; unsigned i; } v; v.i = ((unsigned)u) << 16; return v.f;
}
__device__ __forceinline__ ushort f2bu(float f) {
    __hip_bfloat16 h = __float2bfloat16(f);
    return *(ushort*)&h;
}
__device__ __forceinline__ float ubits(unsigned u) {
    union { unsigned i; float f; } v; v.i = u; return v.f;
}
__device__ __forceinline__ void unpk(unsigned d, float& lo, float& hi) {
    lo = ubits(d << 16); hi = ubits(d & 0xffff0000u);
}

__global__ __launch_bounds__(256) void kx_tr(
    const float* __restrict__ x, ushort* __restrict__ XT) {
    int b = blockIdx.y;
    int hw = blockIdx.x * 256 + threadIdx.x;
    const float* xb = x + ((size_t)b * CC) * HW;
    ushort* XTb = XT + ((size_t)b * HW + hw) * 64;
#pragma unroll 2
    for (int c0 = 0; c0 < 64; c0 += 8) {
        ushort v[8];
#pragma unroll
        for (int j = 0; j < 8; j++)
            v[j] = f2bu(xb[(size_t)(c0 + j) * HW + hw]);
        *(short8*)(XTb + c0) = *(short8*)v;
    }
}

// k0 (grid 16): WPS hi/lo swizzled w_proj bf16; WS swizzled w_hidden; wdwT [9][384]
__global__ __launch_bounds__(256) void k0_prep(
    const float* __restrict__ wp, const float* __restrict__ wh,
    const float* __restrict__ wdw,
    ushort* __restrict__ WPSH, ushort* __restrict__ WPSL,
    ushort* __restrict__ WS, float* __restrict__ wdwT) {
    int t0 = blockIdx.x * 256 + threadIdx.x;
    for (int i = t0; i < 8192; i += 4096) {
        int j = i & 7;
        int lane = (i >> 3) & 63;
        int ks = (i >> 9) & 3;
        int mt = i >> 11;
        int o = mt * 16 + (lane & 15);
        int cc = ks * 32 + ((lane >> 4) << 3) + j;
        float w = wp[o * 128 + cc];
        ushort hi = f2bu(w);
        WPSH[i] = hi;
        WPSL[i] = f2bu(w - bu2f(hi));
    }
    for (int i = t0; i < 24576; i += 4096) {
        int j = i & 7;
        int lane = (i >> 3) & 63;
        int ks = (i >> 9) & 1;
        int mt = i >> 10;
        int o = mt * 16 + (lane & 15);
        int k = ks * 32 + ((lane >> 4) << 3) + j;
        WS[i] = f2bu(wh[o * 64 + k]);
    }
    for (int i = t0; i < 3456; i += 4096) {
        int k = i / 384, ch = i - k * 384;
        wdwT[i] = wdw[ch * 9 + k];
    }
}

// ---------- fused k3 helpers ----------

__device__ __forceinline__ void load_afrags(short8 (&a)[4][2],
        const ushort* __restrict__ WSg, int ci, int lane) {
#pragma unroll
    for (int mt = 0; mt < 4; mt++) {
        int mtg = ci * 4 + mt;
#pragma unroll
        for (int ks = 0; ks < 2; ks++)
            a[mt][ks] = *(const short8*)(WSg + ((((mtg << 1) + ks) << 6) + lane) * 8);
    }
}

// 1x1 conv for one 64-ch chunk via MFMA; B-operand from registers.
__device__ __forceinline__ void hid_mfma_store(
    ushort* halo_u, const short8 (&a)[4][2], const short8 (&bfr)[2][2],
    const bool (&img)[2], const bool (&live)[2], const int (&pxv)[2],
    const float* __restrict__ bh, int ci, int wave, int quad) {
#pragma unroll
    for (int s = 0; s < 2; s++) {
        if (wave + s * 4 > 6) continue;          // 7 active n-tiles (112 px >= 100)
        floatx4 acc[4];
#pragma unroll
        for (int mt = 0; mt < 4; mt++) {
            acc[mt] = (floatx4){0.f, 0.f, 0.f, 0.f};
            acc[mt] = __builtin_amdgcn_mfma_f32_16x16x32_bf16(a[mt][0], bfr[s][0], acc[mt], 0, 0, 0);
            acc[mt] = __builtin_amdgcn_mfma_f32_16x16x32_bf16(a[mt][1], bfr[s][1], acc[mt], 0, 0, 0);
        }
        int px = pxv[s];
#pragma unroll
        for (int mt = 0; mt < 4; mt++) {
            int chl = mt * 16 + quad * 4;
            float4 bv = *(const float4*)(bh + ci * 64 + chl);
            unsigned d0 = 0u, d1 = 0u;
            if (img[s]) {
                d0 = (unsigned)f2bu(acc[mt][0] + bv.x) | ((unsigned)f2bu(acc[mt][1] + bv.y) << 16);
                d1 = (unsigned)f2bu(acc[mt][2] + bv.z) | ((unsigned)f2bu(acc[mt][3] + bv.w) << 16);
            }
            if (live[s])
                *(uint2v*)(halo_u + px * HS + chl) = (uint2v){d0, d1};
        }
    }
}

// dw 3x3 for 64 q-or-k channels. FMA order identical to old k2.
__device__ __forceinline__ void dw_qk(const ushort* halo_u, ushort* dst,
        const float* __restrict__ wdwT, const float* __restrict__ bdw,
        int gcb, int rowbase, int tid) {
    int c2 = tid & 31, po = tid >> 5;
    int gch = gcb + c2 * 2;
    float w0[9], w1[9];
#pragma unroll
    for (int k = 0; k < 9; k++) {
        w0[k] = wdwT[k * 384 + gch];
        w1[k] = wdwT[k * 384 + gch + 1];
    }
    float b0 = bdw[gch], b1 = bdw[gch + 1];
    float a0[8], a1[8];
#pragma unroll
    for (int c = 0; c < 8; c++) { a0[c] = b0; a1[c] = b1; }
#pragma unroll
    for (int dr = 0; dr < 3; dr++) {
        int hb = (po + dr) * 10;
        float hx[10], hy[10];
#pragma unroll
        for (int i = 0; i < 10; i++) {
            unsigned d = *(const unsigned*)(halo_u + (hb + i) * HS + c2 * 2);
            unpk(d, hx[i], hy[i]);
        }
#pragma unroll
        for (int c = 0; c < 8; c++)
#pragma unroll
            for (int dc = 0; dc < 3; dc++) {
                a0[c] += w0[dr * 3 + dc] * hx[c + dc];
                a1[c] += w1[dr * 3 + dc] * hy[c + dc];
            }
    }
    ushort* r0p = dst + (rowbase + c2 * 2) * QSU + po * 8;
    ushort* r1p = r0p + QSU;
    unsigned p0 = (unsigned)f2bu(a0[0]) | ((unsigned)f2bu(a0[1]) << 16);
    unsigned p1 = (unsigned)f2bu(a0[2]) | ((unsigned)f2bu(a0[3]) << 16);
    unsigned p2 = (unsigned)f2bu(a0[4]) | ((unsigned)f2bu(a0[5]) << 16);
    unsigned p3 = (unsigned)f2bu(a0[6]) | ((unsigned)f2bu(a0[7]) << 16);
    *(uint2v*)(r0p) = (uint2v){p0, p1};
    *(uint2v*)(r0p + 4) = (uint2v){p2, p3};
    p0 = (unsigned)f2bu(a1[0]) | ((unsigned)f2bu(a1[1]) << 16);
    p1 = (unsigned)f2bu(a1[2]) | ((unsigned)f2bu(a1[3]) << 16);
    p2 = (unsigned)f2bu(a1[4]) | ((unsigned)f2bu(a1[5]) << 16);
    p3 = (unsigned)f2bu(a1[6]) | ((unsigned)f2bu(a1[7]) << 16);
    *(uint2v*)(r1p) = (uint2v){p0, p1};
    *(uint2v*)(r1p + 4) = (uint2v){p2, p3};
}

// dw 3x3 for 64 v channels + LN-apply, results kept in registers (tp[16]).
__device__ __forceinline__ void dw_v_collect(const ushort* halo_u, const float* tb,
        const float* __restrict__ wdwT, const float* __restrict__ bdw,
        const float* __restrict__ lnw, const float* __restrict__ lnb,
        int gcb, int pix, int cj, float mu, float rsig, float (&tp)[16]) {
    int r = pix >> 3, cs = pix & 7;
    int ch0 = __builtin_amdgcn_readfirstlane(gcb + cj * 16);
    int ccs = ch0 - 256;
    float acc[16];
#pragma unroll
    for (int jj = 0; jj < 16; jj++) acc[jj] = bdw[ch0 + jj];
#pragma unroll
    for (int dr = 0; dr < 3; dr++) {
#pragma unroll
        for (int dc = 0; dc < 3; dc++) {
            int npx = (r + dr) * 10 + cs + dc;
            const ushort* hp = halo_u + npx * HS + cj * 16;
            uint2v d0 = *(const uint2v*)(hp);
            uint2v d1 = *(const uint2v*)(hp + 4);
            uint2v d2 = *(const uint2v*)(hp + 8);
            uint2v d3 = *(const uint2v*)(hp + 12);
            unsigned dd[8] = {d0.x, d0.y, d1.x, d1.y, d2.x, d2.y, d3.x, d3.y};
#pragma unroll
            for (int jj = 0; jj < 16; jj++) {
                unsigned u = dd[jj >> 1];
                float hv = (jj & 1) ? ubits(u & 0xffff0000u) : ubits(u << 16);
                acc[jj] += wdwT[(dr * 3 + dc) * 384 + ch0 + jj] * hv;
            }
        }
    }
#pragma unroll
    for (int jj = 0; jj < 16; jj++) {
        int cc = ccs + jj;
        float vv = bu2f(f2bu(acc[jj]));   // v passes through bf16 (matches old pipeline)
        float tv = tb[cc * TS + pix];
        tp[jj] = ((tv - mu) * rsig * lnw[cc] + lnb[cc]) * vv;
    }
}

__device__ __forceinline__ void split_store(ushort* tBh, ushort* tBl,
        const float (&tp)[16], int pix, int colbase) {
    ushort hi[16], lo[16];
#pragma unroll
    for (int jj = 0; jj < 16; jj++) {
        ushort h = f2bu(tp[jj]);
        hi[jj] = h;
        lo[jj] = f2bu(tp[jj] - bu2f(h));
    }
    *(short8*)(tBh + pix * TBS + colbase) = *(short8*)hi;
    *(short8*)(tBh + pix * TBS + colbase + 8) = *(short8*)(hi + 8);
    *(short8*)(tBl + pix * TBS + colbase) = *(short8*)lo;
    *(short8*)(tBl + pix * TBS + colbase + 8) = *(short8*)(lo + 8);
}

// k3: fully fused. grid (1024, 4) = (patch, batch). LDS 51,200B.
// launch_bounds (256,2): VGPR cap 256 — the r13 config that kept qr resident.
__global__ __launch_bounds__(256, 2) void k3_mega(
    const ushort* __restrict__ XT0, const ushort* __restrict__ WSg,
    const float* __restrict__ bh,
    const ushort* __restrict__ WPSH, const ushort* __restrict__ WPSL,
    const float* __restrict__ bp, const float* __restrict__ lnw,
    const float* __restrict__ lnb, const float* __restrict__ wdwT,
    const float* __restrict__ bdw, float* __restrict__ outT) {
    __shared__ float SH[12800];            // 51,200 B
    ushort* qb_u = (ushort*)SH;            // bf16 [128][68]   bytes 0..17407
    ushort* kb_u = (ushort*)SH + 8704;     // bf16 [128][68]   bytes 17408..34815
    float* tb = SH;                        // f32 [128][68] overlay (after B)
    float* red = SH + 8704;                // 512 f            bytes 34816..36863
    ushort* halo_u = (ushort*)SH + 18432;  // [100][68]u       bytes 36864..50463
    ushort* tBh = (ushort*)SH;             // [64][136]u overlay of tb (after D)
    ushort* tBl = (ushort*)SH + 8704;      // [64][136]u
    float* outS = SH;                      // [64][68] f32 overlay (after E MFMA)

    int tid = threadIdx.x;
    int lane = tid & 63, wave = tid >> 6;
    int lane15 = lane & 15, quad = lane >> 4;
    int b = blockIdx.y;
    const ushort* XT = XT0 + (size_t)b * HW * 64;
    int bid = blockIdx.x;
    int p = ((bid & 7) << 7) | (bid >> 3);   // XCD swizzle
    int prow = p >> 5, pcol = p & 31;
    int r0 = prow * 8, c0 = pcol * 8;

    // ---- B-fragments (x-patch) -> registers, once for all 6 chunks ----
    short8 bfr[2][2];
    bool img[2], live[2];
    int pxv[2];
#pragma unroll
    for (int s = 0; s < 2; s++) {
        int nt = wave + s * 4;
        int px = nt * 16 + lane15;
        pxv[s] = px;
        live[s] = (nt <= 6) && (px < 100);
        int hr = px / 10, hc = px - hr * 10;
        int gr = r0 - 1 + hr, gc = c0 - 1 + hc;
        img[s] = live[s] && ((unsigned)gr < 256u) && ((unsigned)gc < 256u);
        size_t gidx = img[s] ? (size_t)(gr * 256 + gc) * 64 : 0;
        short8 z = (short8){0, 0, 0, 0, 0, 0, 0, 0};
        short8 t0 = *(const short8*)(XT + gidx + quad * 8);
        short8 t1 = *(const short8*)(XT + gidx + 32 + quad * 8);
        bfr[s][0] = img[s] ? t0 : z;
        bfr[s][1] = img[s] ? t1 : z;
    }

    // ---- q/k: 4 chunks of {1x1 MFMA -> halo, dw 3x3 -> qb/kb}; a-frags dbuf ----
    short8 aA[4][2], aB[4][2];
    load_afrags(aA, WSg, 0, lane);
#pragma unroll
    for (int ci = 0; ci < 4; ci++) {
        if (ci) __syncthreads();
        hid_mfma_store(halo_u, aA, bfr, img, live, pxv, bh, ci, wave, quad);
        load_afrags(aB, WSg, ci + 1, lane);
        __syncthreads();
        dw_qk(halo_u, (ci < 2 ? qb_u : kb_u), wdwT, bdw, ci * 64, (ci & 1) * 64, tid);
#pragma unroll
        for (int mt = 0; mt < 4; mt++)
#pragma unroll
            for (int ks = 0; ks < 2; ks++) aA[mt][ks] = aB[mt][ks];
    }
    __syncthreads();

    // ---- Phase B: 2D circular conv (fully unrolled, qr statically indexed) ----
    int c = tid >> 1, h = tid & 1;
    float qr[64];
    {
        const ushort* qrow = qb_u + c * QSU;
#pragma unroll
        for (int j = 0; j < 16; j++) {
            uint2v d = *(const uint2v*)(qrow + 4 * j);
            unpk(d.x, qr[4 * j], qr[4 * j + 1]);
            unpk(d.y, qr[4 * j + 2], qr[4 * j + 3]);
        }
    }
    float acc[8][4];
#pragma unroll
    for (int r = 0; r < 8; r++)
#pragma unroll
        for (int sc = 0; sc < 4; sc++) acc[r][sc] = 0.f;
    {
        const ushort* krow = kb_u + c * QSU;
#pragma unroll
        for (int m = 0; m < 8; m++) {
            float kr[8];
#pragma unroll
            for (int u2 = 0; u2 < 4; u2++) {
                int colo = (u2 * 2 + 4 * h) & 7;
                unsigned d = *(const unsigned*)(krow + m * 8 + colo);
                unpk(d, kr[u2 * 2], kr[u2 * 2 + 1]);
            }
#pragma unroll
            for (int r = 0; r < 8; r++) {
                int i = (r - m) & 7;
#pragma unroll
                for (int sc = 0; sc < 4; sc++)
#pragma unroll
                    for (int j = 0; j < 8; j++)
                        acc[r][sc] += qr[i * 8 + j] * kr[(sc - j) & 7];
            }
        }
    }
    __syncthreads();                          // B reads done -> tb overlay safe

    // ---- Phase C: FRESH a-frag defs (aA/aB dead across B); t -> tb;
    //      chunk-4 MFMA into halo; chunk-5 frags ----
    load_afrags(aA, WSg, 4, lane);            // redefinition: chunk 4 (same values
                                              // the loop prefetched; loop copy DCEs)
#pragma unroll
    for (int r = 0; r < 8; r++) {
        float4 v = {acc[r][0], acc[r][1], acc[r][2], acc[r][3]};
        *(float4*)(tb + c * TS + r * 8 + h * 4) = v;
    }
    hid_mfma_store(halo_u, aA, bfr, img, live, pxv, bh, 4, wave, quad);
    load_afrags(aB, WSg, 5, lane);            // redefinition: chunk 5
    __syncthreads();                          // tb ready AND halo4 ready

    // ---- LN stats ----
    int pix = tid & 63, cg = tid >> 6;
    float sum = 0.f, sq = 0.f;
#pragma unroll
    for (int j = 0; j < 32; j++) {
        int cc = cg * 32 + j;
        float v = tb[cc * TS + pix];
        sum += v; sq += v * v;
    }
    red[cg * 64 + pix] = sum;
    red[256 + cg * 64 + pix] = sq;
    __syncthreads();
    float ts = red[pix] + red[64 + pix] + red[128 + pix] + red[192 + pix];
    float tq = red[256 + pix] + red[320 + pix] + red[384 + pix] + red[448 + pix];
    float mu = ts * (1.f / 128.f);
    float var = tq * (1.f / 128.f) - mu * mu;
    float rsig = rsqrtf(var + 1e-5f);

    // ---- v chunks 4,5: dw + LN-apply -> registers ----
    float tpA[16], tpB[16];
    dw_v_collect(halo_u, tb, wdwT, bdw, lnw, lnb, 256, pix, cg, mu, rsig, tpA);
    __syncthreads();                          // halo4 reads done
    hid_mfma_store(halo_u, aB, bfr, img, live, pxv, bh, 5, wave, quad);
    __syncthreads();                          // halo5 ready
    dw_v_collect(halo_u, tb, wdwT, bdw, lnw, lnb, 320, pix, cg, mu, rsig, tpB);
    __syncthreads();                          // ALL tb reads + halo reads done

    // ---- D3: bf16 hi/lo split of t, px-major into tB (overlay of tb) ----
    split_store(tBh, tBl, tpA, pix, cg * 16);
    split_store(tBh, tBl, tpB, pix, 64 + cg * 16);
    __syncthreads();                          // tB ready

    // ---- Phase E: proj 64x64x128 via MFMA (hi/lo 3-term) ----
    short8 bhf[4], blf[4];
#pragma unroll
    for (int ks = 0; ks < 4; ks++) {
        const int rb = (wave * 16 + lane15) * TBS + ks * 32 + quad * 8;
        bhf[ks] = *(const short8*)(tBh + rb);
        blf[ks] = *(const short8*)(tBl + rb);
    }
    floatx4 pacc[4];
#pragma unroll
    for (int mt = 0; mt < 4; mt++) {
        float4 bv = *(const float4*)(bp + mt * 16 + quad * 4);
        pacc[mt] = (floatx4){bv.x, bv.y, bv.z, bv.w};
    }
#pragma unroll
    for (int mt = 0; mt < 4; mt++) {
#pragma unroll
        for (int ks = 0; ks < 4; ks++) {
            short8 ah = *(const short8*)(WPSH + (((mt * 4 + ks) << 6) + lane) * 8);
            short8 al = *(const short8*)(WPSL + (((mt * 4 + ks) << 6) + lane) * 8);
            pacc[mt] = __builtin_amdgcn_mfma_f32_16x16x32_bf16(ah, bhf[ks], pacc[mt], 0, 0, 0);
            pacc[mt] = __builtin_amdgcn_mfma_f32_16x16x32_bf16(ah, blf[ks], pacc[mt], 0, 0, 0);
            pacc[mt] = __builtin_amdgcn_mfma_f32_16x16x32_bf16(al, bhf[ks], pacc[mt], 0, 0, 0);
        }
    }
    __syncthreads();                          // all tB reads done -> outS overlay safe

    // ---- stage to outS [px][o] and write outT contiguously ----
#pragma unroll
    for (int mt = 0; mt < 4; mt++) {
        float4 v = {pacc[mt][0], pacc[mt][1], pacc[mt][2], pacc[mt][3]};
        *(float4*)(outS + (wave * 16 + lane15) * OSS + mt * 16 + quad * 4) = v;
    }
    __syncthreads();
    {
        int px = tid >> 2, oq = (tid & 3) * 16;
        float* g = outT + ((size_t)(b * 1024 + p) * 64 + px) * 64 + oq;
        const float* srow = outS + px * OSS + oq;
#pragma unroll
        for (int k = 0; k < 4; k++)
            *(float4*)(g + k * 4) = *(const float4*)(srow + k * 4);
    }
}

// k4: outT [b][p][px][o] -> out [b][o][row][col]. grid (64, 4), 256 thr.
__global__ __launch_bounds__(256) void k4_tr(
    const float* __restrict__ outT, float* __restrict__ out) {
    int b = blockIdx.y;
    int xb = blockIdx.x;
    int pr = xb >> 1, half = xb & 1;
    int tid = threadIdx.x;
    int c128 = tid & 127, rr = tid >> 7;
    int col = half * 128 + c128;
    int p = pr * 32 + (col >> 3);
    int cs = col & 7;
    const float* tbase = outT + (size_t)(b * 1024 + p) * 4096;
    float* obase = out + ((size_t)b * 64) * 65536 + col;
#pragma unroll
    for (int r4 = 0; r4 < 4; r4++) {
        int r = rr * 4 + r4;
        int px = r * 8 + cs;
        const float* src = tbase + (size_t)px * 64;
        float v[64];
#pragma unroll
        for (int k = 0; k < 16; k++)
            *(float4*)(v + k * 4) = *(const float4*)(src + k * 4);
        float* dst = obase + (size_t)(pr * 8 + r) * 256;
#pragma unroll
        for (int o = 0; o < 64; o++)
            dst[(size_t)o * 65536] = v[o];
    }
}

extern "C" void kernel_launch(void* const* d_in, const int* in_sizes, int n_in,
                              void* d_out, int out_size, void* d_ws, size_t ws_size,
                              hipStream_t stream) {
    (void)in_sizes; (void)n_in; (void)out_size; (void)ws_size;
    const float* x   = (const float*)d_in[0];
    const float* wh  = (const float*)d_in[1];
    const float* bh  = (const float*)d_in[2];
    const float* wdw = (const float*)d_in[3];
    const float* bdw = (const float*)d_in[4];
    const float* wp  = (const float*)d_in[5];
    const float* bp  = (const float*)d_in[6];
    const float* lnw = (const float*)d_in[7];
    const float* lnb = (const float*)d_in[8];
    float* out = (float*)d_out;

    char* ws = (char*)d_ws;
    ushort* WPSH = (ushort*)(ws + WPSH_OFF);
    ushort* WPSL = (ushort*)(ws + WPSL_OFF);
    ushort* WS = (ushort*)(ws + WS_OFF);
    float* wdwT = (float*)(ws + WDWT_OFF);
    ushort* XT = (ushort*)(ws + XT_OFF);
    float* outT = (float*)(ws + OUTT_OFF);

    kx_tr<<<dim3(256, 4), dim3(256), 0, stream>>>(x, XT);
    k0_prep<<<dim3(16), dim3(256), 0, stream>>>(wp, wh, wdw, WPSH, WPSL, WS, wdwT);
    k3_mega<<<dim3(1024, 4), dim3(256), 0, stream>>>(
        XT, WS, bh, WPSH, WPSL, bp, lnw, lnb, wdwT, bdw, outT);
    k4_tr<<<dim3(64, 4), dim3(256), 0, stream>>>(outT, out);
}